// Round 1
// baseline (658.650 us; speedup 1.0000x reference)
//
#include <hip/hip_runtime.h>
#include <hip/hip_bf16.h>
#include <stdint.h>
#include <stddef.h>

#define NV 2048
#define NE 8192

typedef __bf16 bf16_t;
typedef __bf16 bf16x4 __attribute__((ext_vector_type(4)));
typedef __bf16 bf16x8 __attribute__((ext_vector_type(8)));
typedef float f32x4 __attribute__((ext_vector_type(4)));

__device__ static inline void load_lds16(const void* g, void* lds) {
  __builtin_amdgcn_global_load_lds(
      (const __attribute__((address_space(1))) void*)g,
      (__attribute__((address_space(3))) void*)lds,
      16, 0, 0);
}

// w[e] = dot(H_e[e,:], p[:])   one wave per row
__global__ void k_w(const float* __restrict__ He, const float* __restrict__ p,
                    float* __restrict__ w) {
  int wave = threadIdx.x >> 6;
  int lane = threadIdx.x & 63;
  int e = blockIdx.x * 4 + wave;
  float v = He[(size_t)e * 128 + lane] * p[lane]
          + He[(size_t)e * 128 + 64 + lane] * p[64 + lane];
#pragma unroll
  for (int off = 32; off > 0; off >>= 1) v += __shfl_down(v, off, 64);
  if (lane == 0) w[e] = v;
}

// A[i,e] = bf16(T[i,e]*w[e]);  B[i,e] = bf16(T[i,e])
__global__ void k_conv(const float* __restrict__ T, const float* __restrict__ w,
                       bf16_t* __restrict__ A, bf16_t* __restrict__ B) {
  size_t idx = (size_t)blockIdx.x * 256 + threadIdx.x;  // one float4 each
  size_t base = idx * 4;
  int col = (int)(base & (NE - 1));
  f32x4 t = *(const f32x4*)(T + base);
  f32x4 w4 = *(const f32x4*)(w + col);
  bf16x4 a, b;
  a.x = (bf16_t)(t.x * w4.x); a.y = (bf16_t)(t.y * w4.y);
  a.z = (bf16_t)(t.z * w4.z); a.w = (bf16_t)(t.w * w4.w);
  b.x = (bf16_t)t.x; b.y = (bf16_t)t.y; b.z = (bf16_t)t.z; b.w = (bf16_t)t.w;
  *(bf16x4*)(A + base) = a;
  *(bf16x4*)(B + base) = b;
}

// HW[j,o] = sum_k H_v[j,k] * weight[k,o]   (f32, small)
__global__ void k_hw(const float* __restrict__ Hv, const float* __restrict__ Wt,
                     float* __restrict__ HW) {
  int t = blockIdx.x * 256 + threadIdx.x;  // 262144 outputs
  int o = t & 127, j = t >> 7;
  const float* hv = Hv + (size_t)j * 128;
  float acc = 0.f;
#pragma unroll 4
  for (int k = 0; k < 128; ++k) acc += hv[k] * Wt[k * 128 + o];
  HW[t] = acc;
}

// adjA[i,j] = (i==j ? 1 : sum_e A[i,e]*B[j,e]) * adj_v[i,j]
// m97-style 128x128 tile, BK=64, 256 threads (2x2 waves of 64x64)
__global__ void k_gemm1(const bf16_t* __restrict__ A, const bf16_t* __restrict__ B,
                        const float* __restrict__ adj_v, float* __restrict__ adjA) {
  __shared__ bf16_t As[128 * 64];
  __shared__ bf16_t Bs[128 * 64];
  const int t = threadIdx.x;
  const int lane = t & 63;
  const int wv = t >> 6;
  const int wm = wv >> 1, wn = wv & 1;
  const int i0 = blockIdx.y * 128, j0 = blockIdx.x * 128;

  f32x4 acc[4][4] = {};

  const int lrow = t >> 3;          // 0..31, +32 per staging iter
  const int lcol = (t & 7) * 8;     // bf16 column start within 64
  const bf16_t* Ag = A + (size_t)(i0 + lrow) * NE + lcol;
  const bf16_t* Bg = B + (size_t)(j0 + lrow) * NE + lcol;

  for (int k0 = 0; k0 < NE; k0 += 64) {
    __syncthreads();
#pragma unroll
    for (int it = 0; it < 4; ++it) {
      load_lds16(Ag + (size_t)(it * 32) * NE + k0, (char*)As + (it * 256 + t) * 16);
      load_lds16(Bg + (size_t)(it * 32) * NE + k0, (char*)Bs + (it * 256 + t) * 16);
    }
    __syncthreads();
#pragma unroll
    for (int kk = 0; kk < 64; kk += 32) {
      bf16x8 af[4], bfr[4];
#pragma unroll
      for (int mt = 0; mt < 4; ++mt)
        af[mt] = *(const bf16x8*)&As[(wm * 64 + mt * 16 + (lane & 15)) * 64 + kk + (lane >> 4) * 8];
#pragma unroll
      for (int nt = 0; nt < 4; ++nt)
        bfr[nt] = *(const bf16x8*)&Bs[(wn * 64 + nt * 16 + (lane & 15)) * 64 + kk + (lane >> 4) * 8];
#pragma unroll
      for (int mt = 0; mt < 4; ++mt)
#pragma unroll
        for (int nt = 0; nt < 4; ++nt)
          acc[mt][nt] = __builtin_amdgcn_mfma_f32_16x16x32_bf16(af[mt], bfr[nt], acc[mt][nt], 0, 0, 0);
    }
  }

#pragma unroll
  for (int mt = 0; mt < 4; ++mt) {
#pragma unroll
    for (int nt = 0; nt < 4; ++nt) {
      int gc = j0 + wn * 64 + nt * 16 + (lane & 15);
#pragma unroll
      for (int r = 0; r < 4; ++r) {
        int gr = i0 + wm * 64 + mt * 16 + (lane >> 4) * 4 + r;
        float v = acc[mt][nt][r];
        if (gr == gc) v = 1.0f;
        adjA[(size_t)gr * NV + gc] = v * adj_v[(size_t)gr * NV + gc];
      }
    }
  }
}

// out[i,o] = bias[o] + sum_k adjA[i,k]*HW[k,o]   (f32, LDS-staged adjA rows)
__global__ void k_gemm2(const float* __restrict__ adjA, const float* __restrict__ HW,
                        const float* __restrict__ bias, float* __restrict__ out) {
  __shared__ float tile[8 * 256];
  const int t = threadIdx.x;
  const int o = t & 127;
  const int half = t >> 7;
  const int i0 = blockIdx.x * 8;
  float acc[4] = {0.f, 0.f, 0.f, 0.f};
  for (int kb = 0; kb < NV; kb += 256) {
    __syncthreads();
#pragma unroll
    for (int it = 0; it < 8; ++it) {
      int idx = it * 256 + t;  // row = idx>>8, col = idx&255
      tile[idx] = adjA[(size_t)(i0 + (idx >> 8)) * NV + kb + (idx & 255)];
    }
    __syncthreads();
    const float* trow = tile + (half * 4) * 256;
#pragma unroll 4
    for (int k = 0; k < 256; ++k) {
      float h = HW[(size_t)(kb + k) * 128 + o];
      acc[0] += trow[k] * h;
      acc[1] += trow[256 + k] * h;
      acc[2] += trow[512 + k] * h;
      acc[3] += trow[768 + k] * h;
    }
  }
  float bo = bias[o];
#pragma unroll
  for (int r = 0; r < 4; ++r)
    out[(size_t)(i0 + half * 4 + r) * 128 + o] = acc[r] + bo;
}

extern "C" void kernel_launch(void* const* d_in, const int* in_sizes, int n_in,
                              void* d_out, int out_size, void* d_ws, size_t ws_size,
                              hipStream_t stream) {
  const float* Hv     = (const float*)d_in[0];
  const float* He     = (const float*)d_in[1];
  // d_in[2] = adj_e : UNUSED in the node_layer branch
  const float* adj_v  = (const float*)d_in[3];
  const float* T      = (const float*)d_in[4];
  const float* weight = (const float*)d_in[5];
  const float* p      = (const float*)d_in[6];
  const float* bias   = (const float*)d_in[7];
  float* out = (float*)d_out;

  char* ws = (char*)d_ws;
  bf16_t* A_bf = (bf16_t*)ws;                        // 2048*8192*2 = 33554432 B
  bf16_t* B_bf = (bf16_t*)(ws + 33554432);           // 33554432 B
  float*  adjA = (float*)(ws + 67108864);            // 2048*2048*4 = 16777216 B
  float*  HW   = (float*)(ws + 83886080);            // 2048*128*4 = 1048576 B
  float*  w    = (float*)(ws + 84934656);            // 8192*4 B   (~81 MB total)

  k_w<<<NE / 4, 256, 0, stream>>>(He, p, w);
  k_conv<<<(NV * NE / 4) / 256, 256, 0, stream>>>(T, w, A_bf, B_bf);
  k_hw<<<(NV * 128) / 256, 256, 0, stream>>>(Hv, weight, HW);
  dim3 g1(NV / 128, NV / 128);
  k_gemm1<<<g1, 256, 0, stream>>>(A_bf, B_bf, adj_v, adjA);
  k_gemm2<<<NV / 8, 256, 0, stream>>>(adjA, HW, bias, out);
  hipMemcpyAsync(out + (size_t)NV * 128, He, (size_t)NE * 128 * sizeof(float),
                 hipMemcpyDeviceToDevice, stream);
}

// Round 2
// 650.472 us; speedup vs baseline: 1.0126x; 1.0126x over previous
//
#include <hip/hip_runtime.h>
#include <hip/hip_bf16.h>
#include <stdint.h>
#include <stddef.h>

#define NV 2048
#define NE 8192

typedef __bf16 bf16_t;
typedef __bf16 bf16x4 __attribute__((ext_vector_type(4)));
typedef __bf16 bf16x8 __attribute__((ext_vector_type(8)));
typedef float f32x4 __attribute__((ext_vector_type(4)));

__device__ static inline void load_lds16(const void* g, void* lds) {
  __builtin_amdgcn_global_load_lds(
      (const __attribute__((address_space(1))) void*)g,
      (__attribute__((address_space(3))) void*)lds,
      16, 0, 0);
}

// w[e] = dot(H_e[e,:], p[:])   one wave per row
__global__ void k_w(const float* __restrict__ He, const float* __restrict__ p,
                    float* __restrict__ w) {
  int wave = threadIdx.x >> 6;
  int lane = threadIdx.x & 63;
  int e = blockIdx.x * 4 + wave;
  float v = He[(size_t)e * 128 + lane] * p[lane]
          + He[(size_t)e * 128 + 64 + lane] * p[64 + lane];
#pragma unroll
  for (int off = 32; off > 0; off >>= 1) v += __shfl_down(v, off, 64);
  if (lane == 0) w[e] = v;
}

// A[i,e] = bf16(T[i,e]*w[e]);  B[i,e] = bf16(T[i,e])
__global__ void k_conv(const float* __restrict__ T, const float* __restrict__ w,
                       bf16_t* __restrict__ A, bf16_t* __restrict__ B) {
  size_t idx = (size_t)blockIdx.x * 256 + threadIdx.x;  // one float4 each
  size_t base = idx * 4;
  int col = (int)(base & (NE - 1));
  f32x4 t = *(const f32x4*)(T + base);
  f32x4 w4 = *(const f32x4*)(w + col);
  bf16x4 a, b;
  a.x = (bf16_t)(t.x * w4.x); a.y = (bf16_t)(t.y * w4.y);
  a.z = (bf16_t)(t.z * w4.z); a.w = (bf16_t)(t.w * w4.w);
  b.x = (bf16_t)t.x; b.y = (bf16_t)t.y; b.z = (bf16_t)t.z; b.w = (bf16_t)t.w;
  *(bf16x4*)(A + base) = a;
  *(bf16x4*)(B + base) = b;
}

// HW[j,o] = sum_k H_v[j,k] * weight[k,o]   (f32, small)
__global__ void k_hw(const float* __restrict__ Hv, const float* __restrict__ Wt,
                     float* __restrict__ HW) {
  int t = blockIdx.x * 256 + threadIdx.x;  // 262144 outputs
  int o = t & 127, j = t >> 7;
  const float* hv = Hv + (size_t)j * 128;
  float acc = 0.f;
#pragma unroll 4
  for (int k = 0; k < 128; ++k) acc += hv[k] * Wt[k * 128 + o];
  HW[t] = acc;
}

// M[i,j] += sum_e A[i,e]*B[j,e]  over K chunk; lower-triangle tiles only.
// grid (136 tiles, 8 K-splits), 256 threads, 128x128 tile, BK=64.
__global__ void k_gemm1(const bf16_t* __restrict__ A, const bf16_t* __restrict__ B,
                        float* __restrict__ M) {
  __shared__ bf16_t As[128 * 64];
  __shared__ bf16_t Bs[128 * 64];
  const int t = threadIdx.x;
  const int lane = t & 63;
  const int wv = t >> 6;
  const int wm = wv >> 1, wn = wv & 1;

  // decode lower-tri tile index
  int tile = blockIdx.x;
  int bi = (int)((sqrtf(8.f * tile + 1.f) - 1.f) * 0.5f);
  while ((bi + 1) * (bi + 2) / 2 <= tile) bi++;
  while (bi * (bi + 1) / 2 > tile) bi--;
  int bj = tile - bi * (bi + 1) / 2;
  const int i0 = bi * 128, j0 = bj * 128;
  const int kbeg = blockIdx.y * 1024;

  f32x4 acc[4][4] = {};

  const int lrow = t >> 3;          // 0..31, +32 per staging iter
  const int lcol = (t & 7) * 8;     // bf16 column start within 64
  const bf16_t* Ag = A + (size_t)(i0 + lrow) * NE + lcol;
  const bf16_t* Bg = B + (size_t)(j0 + lrow) * NE + lcol;

  for (int k0 = kbeg; k0 < kbeg + 1024; k0 += 64) {
    __syncthreads();
#pragma unroll
    for (int it = 0; it < 4; ++it) {
      load_lds16(Ag + (size_t)(it * 32) * NE + k0, (char*)As + (it * 256 + t) * 16);
      load_lds16(Bg + (size_t)(it * 32) * NE + k0, (char*)Bs + (it * 256 + t) * 16);
    }
    __syncthreads();
#pragma unroll
    for (int kk = 0; kk < 64; kk += 32) {
      bf16x8 af[4], bfr[4];
#pragma unroll
      for (int mt = 0; mt < 4; ++mt)
        af[mt] = *(const bf16x8*)&As[(wm * 64 + mt * 16 + (lane & 15)) * 64 + kk + (lane >> 4) * 8];
#pragma unroll
      for (int nt = 0; nt < 4; ++nt)
        bfr[nt] = *(const bf16x8*)&Bs[(wn * 64 + nt * 16 + (lane & 15)) * 64 + kk + (lane >> 4) * 8];
#pragma unroll
      for (int mt = 0; mt < 4; ++mt)
#pragma unroll
        for (int nt = 0; nt < 4; ++nt)
          acc[mt][nt] = __builtin_amdgcn_mfma_f32_16x16x32_bf16(af[mt], bfr[nt], acc[mt][nt], 0, 0, 0);
    }
  }

#pragma unroll
  for (int mt = 0; mt < 4; ++mt) {
#pragma unroll
    for (int nt = 0; nt < 4; ++nt) {
      int gc = j0 + wn * 64 + nt * 16 + (lane & 15);
#pragma unroll
      for (int r = 0; r < 4; ++r) {
        int gr = i0 + wm * 64 + mt * 16 + (lane >> 4) * 4 + r;
        atomicAdd(&M[(size_t)gr * NV + gc], acc[mt][nt][r]);
      }
    }
  }
}

// adjA[i,j] = (i==j ? 1 : M[i,j]) * adj_v[i,j], both triangles from lower-tri M.
__global__ void k_mask(const float* __restrict__ M, const float* __restrict__ adj_v,
                       float* __restrict__ adjA) {
  __shared__ float Ms[128 * 129];
  const int t = threadIdx.x;
  int tile = blockIdx.x;
  int bi = (int)((sqrtf(8.f * tile + 1.f) - 1.f) * 0.5f);
  while ((bi + 1) * (bi + 2) / 2 <= tile) bi++;
  while (bi * (bi + 1) / 2 > tile) bi--;
  int bj = tile - bi * (bi + 1) / 2;
  const int i0 = bi * 128, j0 = bj * 128;
  const bool diag = (bi == bj);
#pragma unroll 4
  for (int c = 0; c < 64; ++c) {
    int e = c * 256 + t;
    int r = e >> 7, col = e & 127;
    size_t gidx = (size_t)(i0 + r) * NV + j0 + col;
    float v = M[gidx];
    float vv = (diag && r == col) ? 1.0f : v;
    adjA[gidx] = vv * adj_v[gidx];
    if (!diag) Ms[col * 129 + r] = v;  // transposed stage for mirror
  }
  if (diag) return;
  __syncthreads();
#pragma unroll 4
  for (int c = 0; c < 64; ++c) {
    int e = c * 256 + t;
    int r = e >> 7, col = e & 127;   // mirror row gj=j0+r, col gi=i0+col
    size_t gidx = (size_t)(j0 + r) * NV + i0 + col;
    adjA[gidx] = Ms[r * 129 + col] * adj_v[gidx];
  }
}

// out[i,o] = bias[o] + sum_k adjA[i,k]*HW[k,o]   (f32, LDS-staged adjA rows)
__global__ void k_gemm2(const float* __restrict__ adjA, const float* __restrict__ HW,
                        const float* __restrict__ bias, float* __restrict__ out) {
  __shared__ float tile[4 * 256];
  const int t = threadIdx.x;
  const int o = t & 127;
  const int half = t >> 7;
  const int i0 = blockIdx.x * 4;
  float acc[2] = {0.f, 0.f};
  for (int kb = 0; kb < NV; kb += 256) {
    __syncthreads();
#pragma unroll
    for (int it = 0; it < 4; ++it) {
      int idx = it * 256 + t;  // row = idx>>8, col = idx&255
      tile[idx] = adjA[(size_t)(i0 + (idx >> 8)) * NV + kb + (idx & 255)];
    }
    __syncthreads();
    const float* trow = tile + (half * 2) * 256;
#pragma unroll 4
    for (int k = 0; k < 256; ++k) {
      float h = HW[(size_t)(kb + k) * 128 + o];
      acc[0] += trow[k] * h;
      acc[1] += trow[256 + k] * h;
    }
  }
  float bo = bias[o];
#pragma unroll
  for (int r = 0; r < 2; ++r)
    out[(size_t)(i0 + half * 2 + r) * 128 + o] = acc[r] + bo;
}

extern "C" void kernel_launch(void* const* d_in, const int* in_sizes, int n_in,
                              void* d_out, int out_size, void* d_ws, size_t ws_size,
                              hipStream_t stream) {
  const float* Hv     = (const float*)d_in[0];
  const float* He     = (const float*)d_in[1];
  // d_in[2] = adj_e : UNUSED in the node_layer branch
  const float* adj_v  = (const float*)d_in[3];
  const float* T      = (const float*)d_in[4];
  const float* weight = (const float*)d_in[5];
  const float* p      = (const float*)d_in[6];
  const float* bias   = (const float*)d_in[7];
  float* out = (float*)d_out;

  char* ws = (char*)d_ws;
  bf16_t* A_bf = (bf16_t*)ws;                        // [0, 32 MB)
  bf16_t* B_bf = (bf16_t*)(ws + 33554432);           // [32, 64 MB)
  float*  M    = (float*)(ws + 67108864);            // [64, 80 MB)
  float*  HW   = (float*)(ws + 83886080);            // [80, 81 MB)
  float*  w    = (float*)(ws + 84934656);            // +32 KB
  float*  adjA = (float*)ws;                         // overwrites A_bf after gemm1

  hipMemsetAsync(M, 0, (size_t)NV * NV * sizeof(float), stream);
  k_w<<<NE / 4, 256, 0, stream>>>(He, p, w);
  k_conv<<<(NV * NE / 4) / 256, 256, 0, stream>>>(T, w, A_bf, B_bf);
  k_hw<<<(NV * 128) / 256, 256, 0, stream>>>(Hv, weight, HW);
  dim3 g1(136, 8);
  k_gemm1<<<g1, 256, 0, stream>>>(A_bf, B_bf, M);
  k_mask<<<136, 256, 0, stream>>>(M, adj_v, adjA);
  k_gemm2<<<NV / 4, 256, 0, stream>>>(adjA, HW, bias, out);
  hipMemcpyAsync(out + (size_t)NV * 128, He, (size_t)NE * 128 * sizeof(float),
                 hipMemcpyDeviceToDevice, stream);
}

// Round 3
// 536.085 us; speedup vs baseline: 1.2286x; 1.2134x over previous
//
#include <hip/hip_runtime.h>
#include <hip/hip_bf16.h>
#include <stdint.h>
#include <stddef.h>

#define NV 2048
#define NE 8192
#define KSPLIT 8
#define KCHUNK (NE / KSPLIT)

typedef __bf16 bf16_t;
typedef __bf16 bf16x4 __attribute__((ext_vector_type(4)));
typedef __bf16 bf16x8 __attribute__((ext_vector_type(8)));
typedef float f32x4 __attribute__((ext_vector_type(4)));

__device__ static inline void load_lds16(const void* g, void* lds) {
  __builtin_amdgcn_global_load_lds(
      (const __attribute__((address_space(1))) void*)g,
      (__attribute__((address_space(3))) void*)lds,
      16, 0, 0);
}

__device__ static inline void tile_decode(int tile, int& bi, int& bj) {
  int b = (int)((sqrtf(8.f * tile + 1.f) - 1.f) * 0.5f);
  while ((b + 1) * (b + 2) / 2 <= tile) b++;
  while (b * (b + 1) / 2 > tile) b--;
  bi = b;
  bj = tile - b * (b + 1) / 2;
}

// w[e] = dot(H_e[e,:], p[:])   one wave per row
__global__ void k_w(const float* __restrict__ He, const float* __restrict__ p,
                    float* __restrict__ w) {
  int wave = threadIdx.x >> 6;
  int lane = threadIdx.x & 63;
  int e = blockIdx.x * 4 + wave;
  float v = He[(size_t)e * 128 + lane] * p[lane]
          + He[(size_t)e * 128 + 64 + lane] * p[64 + lane];
#pragma unroll
  for (int off = 32; off > 0; off >>= 1) v += __shfl_down(v, off, 64);
  if (lane == 0) w[e] = v;
}

// A[i,e] = bf16(T[i,e]*w[e]);  B[i,e] = bf16(T[i,e])
__global__ void k_conv(const float* __restrict__ T, const float* __restrict__ w,
                       bf16_t* __restrict__ A, bf16_t* __restrict__ B) {
  size_t idx = (size_t)blockIdx.x * 256 + threadIdx.x;  // one float4 each
  size_t base = idx * 4;
  int col = (int)(base & (NE - 1));
  f32x4 t = *(const f32x4*)(T + base);
  f32x4 w4 = *(const f32x4*)(w + col);
  bf16x4 a, b;
  a.x = (bf16_t)(t.x * w4.x); a.y = (bf16_t)(t.y * w4.y);
  a.z = (bf16_t)(t.z * w4.z); a.w = (bf16_t)(t.w * w4.w);
  b.x = (bf16_t)t.x; b.y = (bf16_t)t.y; b.z = (bf16_t)t.z; b.w = (bf16_t)t.w;
  *(bf16x4*)(A + base) = a;
  *(bf16x4*)(B + base) = b;
}

// HWt[o,j] = bf16( sum_k H_v[j,k] * weight[k,o] )   (transposed, bf16, for MFMA-BT)
__global__ void k_hw(const float* __restrict__ Hv, const float* __restrict__ Wt,
                     bf16_t* __restrict__ HWt) {
  int t = blockIdx.x * 256 + threadIdx.x;  // 262144 outputs
  int o = t & 127, j = t >> 7;
  const float* hv = Hv + (size_t)j * 128;
  float acc = 0.f;
#pragma unroll 4
  for (int k = 0; k < 128; ++k) acc += hv[k] * Wt[k * 128 + o];
  HWt[(size_t)o * NV + j] = (bf16_t)acc;
}

// P[s][i,j] = sum_{e in chunk s} A[i,e]*B[j,e]; lower-triangle tiles only.
// grid (136 tiles, 8 K-splits), 256 threads, 128x128 tile, BK=64. Plain stores.
__global__ void k_gemm1(const bf16_t* __restrict__ A, const bf16_t* __restrict__ B,
                        float* __restrict__ P) {
  __shared__ bf16_t As[128 * 64];
  __shared__ bf16_t Bs[128 * 64];
  const int t = threadIdx.x;
  const int lane = t & 63;
  const int wv = t >> 6;
  const int wm = wv >> 1, wn = wv & 1;

  int bi, bj;
  tile_decode(blockIdx.x, bi, bj);
  const int i0 = bi * 128, j0 = bj * 128;
  const int kbeg = blockIdx.y * KCHUNK;
  float* Mp = P + (size_t)blockIdx.y * NV * NV;

  f32x4 acc[4][4] = {};

  const int lrow = t >> 3;          // 0..31, +32 per staging iter
  const int lcol = (t & 7) * 8;     // bf16 column start within 64
  const bf16_t* Ag = A + (size_t)(i0 + lrow) * NE + lcol;
  const bf16_t* Bg = B + (size_t)(j0 + lrow) * NE + lcol;

  for (int k0 = kbeg; k0 < kbeg + KCHUNK; k0 += 64) {
    __syncthreads();
#pragma unroll
    for (int it = 0; it < 4; ++it) {
      load_lds16(Ag + (size_t)(it * 32) * NE + k0, (char*)As + (it * 256 + t) * 16);
      load_lds16(Bg + (size_t)(it * 32) * NE + k0, (char*)Bs + (it * 256 + t) * 16);
    }
    __syncthreads();
#pragma unroll
    for (int kk = 0; kk < 64; kk += 32) {
      bf16x8 af[4], bfr[4];
#pragma unroll
      for (int mt = 0; mt < 4; ++mt)
        af[mt] = *(const bf16x8*)&As[(wm * 64 + mt * 16 + (lane & 15)) * 64 + kk + (lane >> 4) * 8];
#pragma unroll
      for (int nt = 0; nt < 4; ++nt)
        bfr[nt] = *(const bf16x8*)&Bs[(wn * 64 + nt * 16 + (lane & 15)) * 64 + kk + (lane >> 4) * 8];
#pragma unroll
      for (int mt = 0; mt < 4; ++mt)
#pragma unroll
        for (int nt = 0; nt < 4; ++nt)
          acc[mt][nt] = __builtin_amdgcn_mfma_f32_16x16x32_bf16(af[mt], bfr[nt], acc[mt][nt], 0, 0, 0);
    }
  }

#pragma unroll
  for (int mt = 0; mt < 4; ++mt) {
#pragma unroll
    for (int nt = 0; nt < 4; ++nt) {
      int gc = j0 + wn * 64 + nt * 16 + (lane & 15);
#pragma unroll
      for (int r = 0; r < 4; ++r) {
        int gr = i0 + wm * 64 + mt * 16 + (lane >> 4) * 4 + r;
        Mp[(size_t)gr * NV + gc] = acc[mt][nt][r];
      }
    }
  }
}

// adjA_bf[i,j] = bf16( (i==j ? 1 : sum_s P[s][i,j]) * adj_v[i,j] ), both triangles.
__global__ void k_mask(const float* __restrict__ P, const float* __restrict__ adj_v,
                       bf16_t* __restrict__ adjA) {
  __shared__ float Ms[128 * 129];
  const int t = threadIdx.x;
  int bi, bj;
  tile_decode(blockIdx.x, bi, bj);
  const int i0 = bi * 128, j0 = bj * 128;
  const bool diag = (bi == bj);
#pragma unroll 2
  for (int c = 0; c < 64; ++c) {
    int e = c * 256 + t;
    int r = e >> 7, col = e & 127;
    size_t gidx = (size_t)(i0 + r) * NV + j0 + col;
    float v = 0.f;
#pragma unroll
    for (int s = 0; s < KSPLIT; ++s) v += P[(size_t)s * NV * NV + gidx];
    float vv = (diag && r == col) ? 1.0f : v;
    adjA[gidx] = (bf16_t)(vv * adj_v[gidx]);
    if (!diag) Ms[col * 129 + r] = v;  // transposed stage for mirror
  }
  if (diag) return;
  __syncthreads();
#pragma unroll 2
  for (int c = 0; c < 64; ++c) {
    int e = c * 256 + t;
    int r = e >> 7, col = e & 127;   // mirror: row gj=j0+r, col gi=i0+col
    size_t gidx = (size_t)(j0 + r) * NV + i0 + col;
    adjA[gidx] = (bf16_t)(Ms[r * 129 + col] * adj_v[gidx]);
  }
}

// out[i,o] = bias[o] + sum_k adjA_bf[i,k]*HWt[o,k]   bf16 MFMA, 128x128 tile, K=2048
__global__ void k_gemm2(const bf16_t* __restrict__ adjA, const bf16_t* __restrict__ HWt,
                        const float* __restrict__ bias, float* __restrict__ out) {
  __shared__ bf16_t As[128 * 64];
  __shared__ bf16_t Bs[128 * 64];
  const int t = threadIdx.x;
  const int lane = t & 63;
  const int wv = t >> 6;
  const int wm = wv >> 1, wn = wv & 1;
  const int i0 = blockIdx.x * 128;

  f32x4 acc[4][4] = {};

  const int lrow = t >> 3;
  const int lcol = (t & 7) * 8;
  const bf16_t* Ag = adjA + (size_t)(i0 + lrow) * NV + lcol;
  const bf16_t* Bg = HWt + (size_t)lrow * NV + lcol;

  for (int k0 = 0; k0 < NV; k0 += 64) {
    __syncthreads();
#pragma unroll
    for (int it = 0; it < 4; ++it) {
      load_lds16(Ag + (size_t)(it * 32) * NV + k0, (char*)As + (it * 256 + t) * 16);
      load_lds16(Bg + (size_t)(it * 32) * NV + k0, (char*)Bs + (it * 256 + t) * 16);
    }
    __syncthreads();
#pragma unroll
    for (int kk = 0; kk < 64; kk += 32) {
      bf16x8 af[4], bfr[4];
#pragma unroll
      for (int mt = 0; mt < 4; ++mt)
        af[mt] = *(const bf16x8*)&As[(wm * 64 + mt * 16 + (lane & 15)) * 64 + kk + (lane >> 4) * 8];
#pragma unroll
      for (int nt = 0; nt < 4; ++nt)
        bfr[nt] = *(const bf16x8*)&Bs[(wn * 64 + nt * 16 + (lane & 15)) * 64 + kk + (lane >> 4) * 8];
#pragma unroll
      for (int mt = 0; mt < 4; ++mt)
#pragma unroll
        for (int nt = 0; nt < 4; ++nt)
          acc[mt][nt] = __builtin_amdgcn_mfma_f32_16x16x32_bf16(af[mt], bfr[nt], acc[mt][nt], 0, 0, 0);
    }
  }

#pragma unroll
  for (int mt = 0; mt < 4; ++mt) {
#pragma unroll
    for (int nt = 0; nt < 4; ++nt) {
      int gc = wn * 64 + nt * 16 + (lane & 15);   // output col (o), N=128 total
      float bo = bias[gc];
#pragma unroll
      for (int r = 0; r < 4; ++r) {
        int gr = i0 + wm * 64 + mt * 16 + (lane >> 4) * 4 + r;
        out[(size_t)gr * 128 + gc] = acc[mt][nt][r] + bo;
      }
    }
  }
}

extern "C" void kernel_launch(void* const* d_in, const int* in_sizes, int n_in,
                              void* d_out, int out_size, void* d_ws, size_t ws_size,
                              hipStream_t stream) {
  const float* Hv     = (const float*)d_in[0];
  const float* He     = (const float*)d_in[1];
  // d_in[2] = adj_e : UNUSED in the node_layer branch
  const float* adj_v  = (const float*)d_in[3];
  const float* T      = (const float*)d_in[4];
  const float* weight = (const float*)d_in[5];
  const float* p      = (const float*)d_in[6];
  const float* bias   = (const float*)d_in[7];
  float* out = (float*)d_out;

  char* ws = (char*)d_ws;
  bf16_t* A_bf  = (bf16_t*)ws;                       // [0, 32 MB)
  bf16_t* B_bf  = (bf16_t*)(ws + 33554432);          // [32, 64 MB)
  float*  P     = (float*)(ws + 67108864);           // [64, 192 MB) 8 partials
  bf16_t* adjAb = (bf16_t*)(ws + 201326592);         // [192, 200 MB)
  bf16_t* HWt   = (bf16_t*)(ws + 209715200);         // +512 KB
  float*  w     = (float*)(ws + 210239488);          // +32 KB

  k_w<<<NE / 4, 256, 0, stream>>>(He, p, w);
  k_conv<<<(NV * NE / 4) / 256, 256, 0, stream>>>(T, w, A_bf, B_bf);
  k_hw<<<(NV * 128) / 256, 256, 0, stream>>>(Hv, weight, HWt);
  dim3 g1(136, KSPLIT);
  k_gemm1<<<g1, 256, 0, stream>>>(A_bf, B_bf, P);
  k_mask<<<136, 256, 0, stream>>>(P, adj_v, adjAb);
  k_gemm2<<<NV / 128, 256, 0, stream>>>(adjAb, HWt, bias, out);
  hipMemcpyAsync(out + (size_t)NV * 128, He, (size_t)NE * 128 * sizeof(float),
                 hipMemcpyDeviceToDevice, stream);
}

// Round 4
// 477.282 us; speedup vs baseline: 1.3800x; 1.1232x over previous
//
#include <hip/hip_runtime.h>
#include <hip/hip_bf16.h>
#include <stdint.h>
#include <stddef.h>

#define NV 2048
#define NE 8192
#define KSPLIT 8
#define KCHUNK (NE / KSPLIT)

typedef __bf16 bf16_t;
typedef __bf16 bf16x4 __attribute__((ext_vector_type(4)));
typedef __bf16 bf16x8 __attribute__((ext_vector_type(8)));
typedef float f32x4 __attribute__((ext_vector_type(4)));

__device__ static inline void load_lds16(const void* g, void* lds) {
  __builtin_amdgcn_global_load_lds(
      (const __attribute__((address_space(1))) void*)g,
      (__attribute__((address_space(3))) void*)lds,
      16, 0, 0);
}

__device__ static inline void tile_decode(int tile, int& bi, int& bj) {
  int b = (int)((sqrtf(8.f * tile + 1.f) - 1.f) * 0.5f);
  while ((b + 1) * (b + 2) / 2 <= tile) b++;
  while (b * (b + 1) / 2 > tile) b--;
  bi = b;
  bj = tile - b * (b + 1) / 2;
}

// w[e] = dot(H_e[e,:], p[:])   one wave per row
__global__ void k_w(const float* __restrict__ He, const float* __restrict__ p,
                    float* __restrict__ w) {
  int wave = threadIdx.x >> 6;
  int lane = threadIdx.x & 63;
  int e = blockIdx.x * 4 + wave;
  float v = He[(size_t)e * 128 + lane] * p[lane]
          + He[(size_t)e * 128 + 64 + lane] * p[64 + lane];
#pragma unroll
  for (int off = 32; off > 0; off >>= 1) v += __shfl_down(v, off, 64);
  if (lane == 0) w[e] = v;
}

// A[i,e] = bf16(T[i,e]*w[e]);  B[i,e] = bf16(T[i,e])
__global__ void k_conv(const float* __restrict__ T, const float* __restrict__ w,
                       bf16_t* __restrict__ A, bf16_t* __restrict__ B) {
  size_t idx = (size_t)blockIdx.x * 256 + threadIdx.x;  // one float4 each
  size_t base = idx * 4;
  int col = (int)(base & (NE - 1));
  f32x4 t = *(const f32x4*)(T + base);
  f32x4 w4 = *(const f32x4*)(w + col);
  bf16x4 a, b;
  a.x = (bf16_t)(t.x * w4.x); a.y = (bf16_t)(t.y * w4.y);
  a.z = (bf16_t)(t.z * w4.z); a.w = (bf16_t)(t.w * w4.w);
  b.x = (bf16_t)t.x; b.y = (bf16_t)t.y; b.z = (bf16_t)t.z; b.w = (bf16_t)t.w;
  *(bf16x4*)(A + base) = a;
  *(bf16x4*)(B + base) = b;
}

// HWt[o,j] = bf16( sum_k H_v[j,k] * weight[k,o] )   (transposed, bf16)
__global__ void k_hw(const float* __restrict__ Hv, const float* __restrict__ Wt,
                     bf16_t* __restrict__ HWt) {
  int t = blockIdx.x * 256 + threadIdx.x;
  int o = t & 127, j = t >> 7;
  const float* hv = Hv + (size_t)j * 128;
  float acc = 0.f;
#pragma unroll 4
  for (int k = 0; k < 128; ++k) acc += hv[k] * Wt[k * 128 + o];
  HWt[(size_t)o * NV + j] = (bf16_t)acc;
}

// P[tile][split][128][128](bf16) = partial sum over K chunk; lower-tri tiles only.
// grid (136, 8), 256 threads, 128x128 tile, BK=64. XOR-swizzled LDS (conflict-free).
__global__ void k_gemm1(const bf16_t* __restrict__ A, const bf16_t* __restrict__ B,
                        bf16_t* __restrict__ P) {
  __shared__ bf16_t As[128 * 64];
  __shared__ bf16_t Bs[128 * 64];
  const int t = threadIdx.x;
  const int lane = t & 63;
  const int wv = t >> 6;
  const int wm = wv >> 1, wn = wv & 1;

  int bi, bj;
  tile_decode(blockIdx.x, bi, bj);
  const int i0 = bi * 128, j0 = bj * 128;
  const int kbeg = blockIdx.y * KCHUNK;
  bf16_t* Mp = P + ((size_t)blockIdx.x * KSPLIT + blockIdx.y) * 16384;

  f32x4 acc[4][4] = {};

  // staging: physical slot s=(t&7) of row r holds logical k-block (s+r)&7
  const int lrow = t >> 3;                        // 0..31 (+32 per it)
  const int cb = ((t & 7) + lrow) & 7;            // swizzled global k-block
  const bf16_t* Ag = A + (size_t)(i0 + lrow) * NE + cb * 8;
  const bf16_t* Bg = B + (size_t)(j0 + lrow) * NE + cb * 8;

  for (int k0 = kbeg; k0 < kbeg + KCHUNK; k0 += 64) {
    __syncthreads();
#pragma unroll
    for (int it = 0; it < 4; ++it) {
      load_lds16(Ag + (size_t)(it * 32) * NE + k0, (char*)As + (it * 256 + t) * 16);
      load_lds16(Bg + (size_t)(it * 32) * NE + k0, (char*)Bs + (it * 256 + t) * 16);
    }
    __syncthreads();
#pragma unroll
    for (int kk = 0; kk < 64; kk += 32) {
      bf16x8 af[4], bfr[4];
#pragma unroll
      for (int mt = 0; mt < 4; ++mt) {
        int row = wm * 64 + mt * 16 + (lane & 15);
        int sw = (((kk >> 3) + (lane >> 4)) - row) & 7;
        af[mt] = *(const bf16x8*)&As[row * 64 + sw * 8];
      }
#pragma unroll
      for (int nt = 0; nt < 4; ++nt) {
        int row = wn * 64 + nt * 16 + (lane & 15);
        int sw = (((kk >> 3) + (lane >> 4)) - row) & 7;
        bfr[nt] = *(const bf16x8*)&Bs[row * 64 + sw * 8];
      }
#pragma unroll
      for (int mt = 0; mt < 4; ++mt)
#pragma unroll
        for (int nt = 0; nt < 4; ++nt)
          acc[mt][nt] = __builtin_amdgcn_mfma_f32_16x16x32_bf16(af[mt], bfr[nt], acc[mt][nt], 0, 0, 0);
    }
  }

#pragma unroll
  for (int mt = 0; mt < 4; ++mt) {
#pragma unroll
    for (int nt = 0; nt < 4; ++nt) {
      int tc = wn * 64 + nt * 16 + (lane & 15);
#pragma unroll
      for (int r = 0; r < 4; ++r) {
        int tr = wm * 64 + mt * 16 + (lane >> 4) * 4 + r;
        Mp[tr * 128 + tc] = (bf16_t)acc[mt][nt][r];
      }
    }
  }
}

// adjA_bf[i,j] = bf16( (i==j ? 1 : sum_s P[tile][s][i,j]) * adj_v[i,j] ), both triangles.
__global__ void k_mask(const bf16_t* __restrict__ P, const float* __restrict__ adj_v,
                       bf16_t* __restrict__ adjA) {
  __shared__ float Ms[128 * 129];
  const int t = threadIdx.x;
  int bi, bj;
  tile_decode(blockIdx.x, bi, bj);
  const int i0 = bi * 128, j0 = bj * 128;
  const bool diag = (bi == bj);
  const bf16_t* Pt = P + (size_t)blockIdx.x * (KSPLIT * 16384);
#pragma unroll 2
  for (int c = 0; c < 8; ++c) {
    int e0 = (c * 256 + t) * 8;
    int r = e0 >> 7, col = e0 & 127;
    float v[8] = {};
#pragma unroll
    for (int s = 0; s < KSPLIT; ++s) {
      bf16x8 pv = *(const bf16x8*)(Pt + s * 16384 + e0);
#pragma unroll
      for (int u = 0; u < 8; ++u) v[u] += (float)pv[u];
    }
    size_t g = (size_t)(i0 + r) * NV + j0 + col;
    f32x4 av0 = *(const f32x4*)(adj_v + g);
    f32x4 av1 = *(const f32x4*)(adj_v + g + 4);
    bf16x8 outv;
#pragma unroll
    for (int u = 0; u < 8; ++u) {
      float vv = (diag && r == col + u) ? 1.0f : v[u];
      outv[u] = (bf16_t)(vv * (u < 4 ? av0[u] : av1[u - 4]));
    }
    *(bf16x8*)(adjA + g) = outv;
    if (!diag) {
#pragma unroll
      for (int u = 0; u < 8; ++u) Ms[(col + u) * 129 + r] = v[u];
    }
  }
  if (diag) return;
  __syncthreads();
#pragma unroll 2
  for (int c = 0; c < 8; ++c) {
    int e0 = (c * 256 + t) * 8;
    int r = e0 >> 7, col = e0 & 127;
    size_t g = (size_t)(j0 + r) * NV + i0 + col;
    f32x4 av0 = *(const f32x4*)(adj_v + g);
    f32x4 av1 = *(const f32x4*)(adj_v + g + 4);
    bf16x8 outv;
#pragma unroll
    for (int u = 0; u < 8; ++u)
      outv[u] = (bf16_t)(Ms[r * 129 + col + u] * (u < 4 ? av0[u] : av1[u - 4]));
    *(bf16x8*)(adjA + g) = outv;
  }
}

// P2[split][i][o] = partial of adjA @ HW^T over K chunk of 256. grid (16, 8).
__global__ void k_gemm2(const bf16_t* __restrict__ adjA, const bf16_t* __restrict__ HWt,
                        float* __restrict__ P2) {
  __shared__ bf16_t As[128 * 64];
  __shared__ bf16_t Bs[128 * 64];
  const int t = threadIdx.x;
  const int lane = t & 63;
  const int wv = t >> 6;
  const int wm = wv >> 1, wn = wv & 1;
  const int i0 = blockIdx.x * 128;
  const int kbeg = blockIdx.y * 256;
  float* Pp = P2 + (size_t)blockIdx.y * (NV * 128);

  f32x4 acc[4][4] = {};

  const int lrow = t >> 3;
  const int cb = ((t & 7) + lrow) & 7;
  const bf16_t* Ag = adjA + (size_t)(i0 + lrow) * NV + cb * 8;
  const bf16_t* Bg = HWt + (size_t)lrow * NV + cb * 8;

  for (int k0 = kbeg; k0 < kbeg + 256; k0 += 64) {
    __syncthreads();
#pragma unroll
    for (int it = 0; it < 4; ++it) {
      load_lds16(Ag + (size_t)(it * 32) * NV + k0, (char*)As + (it * 256 + t) * 16);
      load_lds16(Bg + (size_t)(it * 32) * NV + k0, (char*)Bs + (it * 256 + t) * 16);
    }
    __syncthreads();
#pragma unroll
    for (int kk = 0; kk < 64; kk += 32) {
      bf16x8 af[4], bfr[4];
#pragma unroll
      for (int mt = 0; mt < 4; ++mt) {
        int row = wm * 64 + mt * 16 + (lane & 15);
        int sw = (((kk >> 3) + (lane >> 4)) - row) & 7;
        af[mt] = *(const bf16x8*)&As[row * 64 + sw * 8];
      }
#pragma unroll
      for (int nt = 0; nt < 4; ++nt) {
        int row = wn * 64 + nt * 16 + (lane & 15);
        int sw = (((kk >> 3) + (lane >> 4)) - row) & 7;
        bfr[nt] = *(const bf16x8*)&Bs[row * 64 + sw * 8];
      }
#pragma unroll
      for (int mt = 0; mt < 4; ++mt)
#pragma unroll
        for (int nt = 0; nt < 4; ++nt)
          acc[mt][nt] = __builtin_amdgcn_mfma_f32_16x16x32_bf16(af[mt], bfr[nt], acc[mt][nt], 0, 0, 0);
    }
  }

#pragma unroll
  for (int mt = 0; mt < 4; ++mt) {
#pragma unroll
    for (int nt = 0; nt < 4; ++nt) {
      int gc = wn * 64 + nt * 16 + (lane & 15);   // output col o (0..127)
#pragma unroll
      for (int r = 0; r < 4; ++r) {
        int gr = i0 + wm * 64 + mt * 16 + (lane >> 4) * 4 + r;
        Pp[(size_t)gr * 128 + gc] = acc[mt][nt][r];
      }
    }
  }
}

// out[i,o] = sum_s P2[s][i][o] + bias[o]
__global__ void k_bias(const float* __restrict__ P2, const float* __restrict__ bias,
                       float* __restrict__ out) {
  int idx = (blockIdx.x * 256 + threadIdx.x) * 4;  // 2048*128/4 = 65536 threads
  f32x4 acc = {};
#pragma unroll
  for (int s = 0; s < 8; ++s) acc += *(const f32x4*)(P2 + (size_t)s * NV * 128 + idx);
  f32x4 b = *(const f32x4*)(bias + (idx & 127));
  *(f32x4*)(out + idx) = acc + b;
}

extern "C" void kernel_launch(void* const* d_in, const int* in_sizes, int n_in,
                              void* d_out, int out_size, void* d_ws, size_t ws_size,
                              hipStream_t stream) {
  const float* Hv     = (const float*)d_in[0];
  const float* He     = (const float*)d_in[1];
  // d_in[2] = adj_e : UNUSED in the node_layer branch
  const float* adj_v  = (const float*)d_in[3];
  const float* T      = (const float*)d_in[4];
  const float* weight = (const float*)d_in[5];
  const float* p      = (const float*)d_in[6];
  const float* bias   = (const float*)d_in[7];
  float* out = (float*)d_out;

  char* ws = (char*)d_ws;
  bf16_t* A_bf  = (bf16_t*)ws;                       // [0, 32M)
  bf16_t* B_bf  = (bf16_t*)(ws + 33554432);          // [32M, 64M)
  bf16_t* P1    = (bf16_t*)(ws + 67108864);          // 136*8*16384*2 = 34.8 MB
  bf16_t* adjAb = (bf16_t*)(ws + 104857600);         // 8 MB
  float*  P2    = (float*)(ws + 113246208);          // 8*1 MB
  bf16_t* HWt   = (bf16_t*)(ws + 121634816);         // 512 KB
  float*  w     = (float*)(ws + 122155008);          // 32 KB

  k_w<<<NE / 4, 256, 0, stream>>>(He, p, w);
  k_conv<<<(NV * NE / 4) / 256, 256, 0, stream>>>(T, w, A_bf, B_bf);
  k_hw<<<(NV * 128) / 256, 256, 0, stream>>>(Hv, weight, HWt);
  dim3 g1(136, KSPLIT);
  k_gemm1<<<g1, 256, 0, stream>>>(A_bf, B_bf, P1);
  k_mask<<<136, 256, 0, stream>>>(P1, adj_v, adjAb);
  dim3 g2(NV / 128, 8);
  k_gemm2<<<g2, 256, 0, stream>>>(adjAb, HWt, P2);
  k_bias<<<NV * 128 / 4 / 256, 256, 0, stream>>>(P2, bias, out);
  hipMemcpyAsync(out + (size_t)NV * 128, He, (size_t)NE * 128 * sizeof(float),
                 hipMemcpyDeviceToDevice, stream);
}

// Round 5
// 469.410 us; speedup vs baseline: 1.4031x; 1.0168x over previous
//
#include <hip/hip_runtime.h>
#include <hip/hip_bf16.h>
#include <stdint.h>
#include <stddef.h>

#define NV 2048
#define NE 8192
#define KSPLIT 4
#define KCHUNK (NE / KSPLIT)

typedef __bf16 bf16_t;
typedef __bf16 bf16x4 __attribute__((ext_vector_type(4)));
typedef __bf16 bf16x8 __attribute__((ext_vector_type(8)));
typedef float f32x4 __attribute__((ext_vector_type(4)));
typedef float f32x16 __attribute__((ext_vector_type(16)));

__device__ static inline void load_lds16(const void* g, void* lds) {
  __builtin_amdgcn_global_load_lds(
      (const __attribute__((address_space(1))) void*)g,
      (__attribute__((address_space(3))) void*)lds,
      16, 0, 0);
}

__device__ static inline void tile_decode(int tile, int& bi, int& bj) {
  int b = (int)((sqrtf(8.f * tile + 1.f) - 1.f) * 0.5f);
  while ((b + 1) * (b + 2) / 2 <= tile) b++;
  while (b * (b + 1) / 2 > tile) b--;
  bi = b;
  bj = tile - b * (b + 1) / 2;
}

// w[e] = dot(H_e[e,:], p[:])   one wave per row
__global__ void k_w(const float* __restrict__ He, const float* __restrict__ p,
                    float* __restrict__ w) {
  int wave = threadIdx.x >> 6;
  int lane = threadIdx.x & 63;
  int e = blockIdx.x * 4 + wave;
  float v = He[(size_t)e * 128 + lane] * p[lane]
          + He[(size_t)e * 128 + 64 + lane] * p[64 + lane];
#pragma unroll
  for (int off = 32; off > 0; off >>= 1) v += __shfl_down(v, off, 64);
  if (lane == 0) w[e] = v;
}

// A[i,e] = bf16(T[i,e]*w[e]);  B[i,e] = bf16(T[i,e])
__global__ void k_conv(const float* __restrict__ T, const float* __restrict__ w,
                       bf16_t* __restrict__ A, bf16_t* __restrict__ B) {
  size_t idx = (size_t)blockIdx.x * 256 + threadIdx.x;  // one float4 each
  size_t base = idx * 4;
  int col = (int)(base & (NE - 1));
  f32x4 t = *(const f32x4*)(T + base);
  f32x4 w4 = *(const f32x4*)(w + col);
  bf16x4 a, b;
  a.x = (bf16_t)(t.x * w4.x); a.y = (bf16_t)(t.y * w4.y);
  a.z = (bf16_t)(t.z * w4.z); a.w = (bf16_t)(t.w * w4.w);
  b.x = (bf16_t)t.x; b.y = (bf16_t)t.y; b.z = (bf16_t)t.z; b.w = (bf16_t)t.w;
  *(bf16x4*)(A + base) = a;
  *(bf16x4*)(B + base) = b;
}

// HWt[o,j] = bf16( sum_k H_v[j,k] * weight[k,o] )   (transposed, bf16)
__global__ void k_hw(const float* __restrict__ Hv, const float* __restrict__ Wt,
                     bf16_t* __restrict__ HWt) {
  int t = blockIdx.x * 256 + threadIdx.x;
  int o = t & 127, j = t >> 7;
  const float* hv = Hv + (size_t)j * 128;
  float acc = 0.f;
#pragma unroll 4
  for (int k = 0; k < 128; ++k) acc += hv[k] * Wt[k * 128 + o];
  HWt[(size_t)o * NV + j] = (bf16_t)acc;
}

// P[tile][split][128][128](bf16) = partial over K chunk; lower-tri tiles only.
// grid (136, KSPLIT), 256 threads, 128x128 tile, BK=64, 32x32x16 MFMA,
// XOR-swizzled LDS (conflict-free).
__global__ void k_gemm1(const bf16_t* __restrict__ A, const bf16_t* __restrict__ B,
                        bf16_t* __restrict__ P) {
  __shared__ bf16_t As[128 * 64];
  __shared__ bf16_t Bs[128 * 64];
  const int t = threadIdx.x;
  const int lane = t & 63;
  const int wv = t >> 6;
  const int wm = wv >> 1, wn = wv & 1;

  int bi, bj;
  tile_decode(blockIdx.x, bi, bj);
  const int i0 = bi * 128, j0 = bj * 128;
  const int kbeg = blockIdx.y * KCHUNK;
  bf16_t* Mp = P + ((size_t)blockIdx.x * KSPLIT + blockIdx.y) * 16384;

  f32x16 acc[2][2] = {};

  // staging: physical 8-elem slot s=(t&7) of row r holds logical k-block (s+r)&7
  const int lrow = t >> 3;                        // 0..31 (+32 per it)
  const int cb = ((t & 7) + lrow) & 7;            // swizzled global k-block
  const bf16_t* Ag = A + (size_t)(i0 + lrow) * NE + cb * 8;
  const bf16_t* Bg = B + (size_t)(j0 + lrow) * NE + cb * 8;

  for (int k0 = kbeg; k0 < kbeg + KCHUNK; k0 += 64) {
    __syncthreads();
#pragma unroll
    for (int it = 0; it < 4; ++it) {
      load_lds16(Ag + (size_t)(it * 32) * NE + k0, (char*)As + (it * 256 + t) * 16);
      load_lds16(Bg + (size_t)(it * 32) * NE + k0, (char*)Bs + (it * 256 + t) * 16);
    }
    __syncthreads();
#pragma unroll
    for (int kk = 0; kk < 64; kk += 16) {
      bf16x8 af[2], bfr[2];
#pragma unroll
      for (int mt = 0; mt < 2; ++mt) {
        int row = wm * 64 + mt * 32 + (lane & 31);
        int sw = (((kk >> 3) + (lane >> 5)) - row) & 7;
        af[mt] = *(const bf16x8*)&As[row * 64 + sw * 8];
      }
#pragma unroll
      for (int nt = 0; nt < 2; ++nt) {
        int row = wn * 64 + nt * 32 + (lane & 31);
        int sw = (((kk >> 3) + (lane >> 5)) - row) & 7;
        bfr[nt] = *(const bf16x8*)&Bs[row * 64 + sw * 8];
      }
#pragma unroll
      for (int mt = 0; mt < 2; ++mt)
#pragma unroll
        for (int nt = 0; nt < 2; ++nt)
          acc[mt][nt] = __builtin_amdgcn_mfma_f32_32x32x16_bf16(af[mt], bfr[nt], acc[mt][nt], 0, 0, 0);
    }
  }

  // C/D layout (32x32): col = lane&31, row = (reg&3) + 8*(reg>>2) + 4*(lane>>5)
#pragma unroll
  for (int mt = 0; mt < 2; ++mt) {
#pragma unroll
    for (int nt = 0; nt < 2; ++nt) {
      int tc = wn * 64 + nt * 32 + (lane & 31);
#pragma unroll
      for (int reg = 0; reg < 16; ++reg) {
        int tr = wm * 64 + mt * 32 + (reg & 3) + 8 * (reg >> 2) + 4 * (lane >> 5);
        Mp[tr * 128 + tc] = (bf16_t)acc[mt][nt][reg];
      }
    }
  }
}

// adjA_bf[i,j] = bf16( (i==j ? 1 : sum_s P[tile][s][i,j]) * adj_v[i,j] ), both triangles.
__global__ void k_mask(const bf16_t* __restrict__ P, const float* __restrict__ adj_v,
                       bf16_t* __restrict__ adjA) {
  __shared__ float Ms[128 * 129];
  const int t = threadIdx.x;
  int bi, bj;
  tile_decode(blockIdx.x, bi, bj);
  const int i0 = bi * 128, j0 = bj * 128;
  const bool diag = (bi == bj);
  const bf16_t* Pt = P + (size_t)blockIdx.x * (KSPLIT * 16384);
#pragma unroll 2
  for (int c = 0; c < 8; ++c) {
    int e0 = (c * 256 + t) * 8;
    int r = e0 >> 7, col = e0 & 127;
    float v[8] = {};
#pragma unroll
    for (int s = 0; s < KSPLIT; ++s) {
      bf16x8 pv = *(const bf16x8*)(Pt + s * 16384 + e0);
#pragma unroll
      for (int u = 0; u < 8; ++u) v[u] += (float)pv[u];
    }
    size_t g = (size_t)(i0 + r) * NV + j0 + col;
    f32x4 av0 = *(const f32x4*)(adj_v + g);
    f32x4 av1 = *(const f32x4*)(adj_v + g + 4);
    bf16x8 outv;
#pragma unroll
    for (int u = 0; u < 8; ++u) {
      float vv = (diag && r == col + u) ? 1.0f : v[u];
      outv[u] = (bf16_t)(vv * (u < 4 ? av0[u] : av1[u - 4]));
    }
    *(bf16x8*)(adjA + g) = outv;
    if (!diag) {
#pragma unroll
      for (int u = 0; u < 8; ++u) Ms[(col + u) * 129 + r] = v[u];
    }
  }
  if (diag) return;
  __syncthreads();
#pragma unroll 2
  for (int c = 0; c < 8; ++c) {
    int e0 = (c * 256 + t) * 8;
    int r = e0 >> 7, col = e0 & 127;
    size_t g = (size_t)(j0 + r) * NV + i0 + col;
    f32x4 av0 = *(const f32x4*)(adj_v + g);
    f32x4 av1 = *(const f32x4*)(adj_v + g + 4);
    bf16x8 outv;
#pragma unroll
    for (int u = 0; u < 8; ++u)
      outv[u] = (bf16_t)(Ms[r * 129 + col + u] * (u < 4 ? av0[u] : av1[u - 4]));
    *(bf16x8*)(adjA + g) = outv;
  }
}

// P2[split][i][o] = partial of adjA @ HW^T over K chunk of 256. grid (16, 8).
__global__ void k_gemm2(const bf16_t* __restrict__ adjA, const bf16_t* __restrict__ HWt,
                        float* __restrict__ P2) {
  __shared__ bf16_t As[128 * 64];
  __shared__ bf16_t Bs[128 * 64];
  const int t = threadIdx.x;
  const int lane = t & 63;
  const int wv = t >> 6;
  const int wm = wv >> 1, wn = wv & 1;
  const int i0 = blockIdx.x * 128;
  const int kbeg = blockIdx.y * 256;
  float* Pp = P2 + (size_t)blockIdx.y * (NV * 128);

  f32x4 acc[4][4] = {};

  const int lrow = t >> 3;
  const int cb = ((t & 7) + lrow) & 7;
  const bf16_t* Ag = adjA + (size_t)(i0 + lrow) * NV + cb * 8;
  const bf16_t* Bg = HWt + (size_t)lrow * NV + cb * 8;

  for (int k0 = kbeg; k0 < kbeg + 256; k0 += 64) {
    __syncthreads();
#pragma unroll
    for (int it = 0; it < 4; ++it) {
      load_lds16(Ag + (size_t)(it * 32) * NV + k0, (char*)As + (it * 256 + t) * 16);
      load_lds16(Bg + (size_t)(it * 32) * NV + k0, (char*)Bs + (it * 256 + t) * 16);
    }
    __syncthreads();
#pragma unroll
    for (int kk = 0; kk < 64; kk += 32) {
      bf16x8 af[4], bfr[4];
#pragma unroll
      for (int mt = 0; mt < 4; ++mt) {
        int row = wm * 64 + mt * 16 + (lane & 15);
        int sw = (((kk >> 3) + (lane >> 4)) - row) & 7;
        af[mt] = *(const bf16x8*)&As[row * 64 + sw * 8];
      }
#pragma unroll
      for (int nt = 0; nt < 4; ++nt) {
        int row = wn * 64 + nt * 16 + (lane & 15);
        int sw = (((kk >> 3) + (lane >> 4)) - row) & 7;
        bfr[nt] = *(const bf16x8*)&Bs[row * 64 + sw * 8];
      }
#pragma unroll
      for (int mt = 0; mt < 4; ++mt)
#pragma unroll
        for (int nt = 0; nt < 4; ++nt)
          acc[mt][nt] = __builtin_amdgcn_mfma_f32_16x16x32_bf16(af[mt], bfr[nt], acc[mt][nt], 0, 0, 0);
    }
  }

#pragma unroll
  for (int mt = 0; mt < 4; ++mt) {
#pragma unroll
    for (int nt = 0; nt < 4; ++nt) {
      int gc = wn * 64 + nt * 16 + (lane & 15);   // output col o (0..127)
#pragma unroll
      for (int r = 0; r < 4; ++r) {
        int gr = i0 + wm * 64 + mt * 16 + (lane >> 4) * 4 + r;
        Pp[(size_t)gr * 128 + gc] = acc[mt][nt][r];
      }
    }
  }
}

// out[i,o] = sum_s P2[s][i][o] + bias[o]
__global__ void k_bias(const float* __restrict__ P2, const float* __restrict__ bias,
                       float* __restrict__ out) {
  int idx = (blockIdx.x * 256 + threadIdx.x) * 4;  // 2048*128/4 = 65536 threads
  f32x4 acc = {};
#pragma unroll
  for (int s = 0; s < 8; ++s) acc += *(const f32x4*)(P2 + (size_t)s * NV * 128 + idx);
  f32x4 b = *(const f32x4*)(bias + (idx & 127));
  *(f32x4*)(out + idx) = acc + b;
}

extern "C" void kernel_launch(void* const* d_in, const int* in_sizes, int n_in,
                              void* d_out, int out_size, void* d_ws, size_t ws_size,
                              hipStream_t stream) {
  const float* Hv     = (const float*)d_in[0];
  const float* He     = (const float*)d_in[1];
  // d_in[2] = adj_e : UNUSED in the node_layer branch
  const float* adj_v  = (const float*)d_in[3];
  const float* T      = (const float*)d_in[4];
  const float* weight = (const float*)d_in[5];
  const float* p      = (const float*)d_in[6];
  const float* bias   = (const float*)d_in[7];
  float* out = (float*)d_out;

  char* ws = (char*)d_ws;
  bf16_t* A_bf  = (bf16_t*)ws;                       // [0, 32M)
  bf16_t* B_bf  = (bf16_t*)(ws + 33554432);          // [32M, 64M)
  bf16_t* P1    = (bf16_t*)(ws + 67108864);          // 136*4*16384*2 = 17.8 MB
  bf16_t* adjAb = (bf16_t*)(ws + 100663296);         // 8 MB
  float*  P2    = (float*)(ws + 109051904);          // 8 MB
  bf16_t* HWt   = (bf16_t*)(ws + 117440512);         // 512 KB
  float*  w     = (float*)(ws + 117964800);          // 32 KB

  k_w<<<NE / 4, 256, 0, stream>>>(He, p, w);
  k_conv<<<(NV * NE / 4) / 256, 256, 0, stream>>>(T, w, A_bf, B_bf);
  k_hw<<<(NV * 128) / 256, 256, 0, stream>>>(Hv, weight, HWt);
  dim3 g1(136, KSPLIT);
  k_gemm1<<<g1, 256, 0, stream>>>(A_bf, B_bf, P1);
  k_mask<<<136, 256, 0, stream>>>(P1, adj_v, adjAb);
  dim3 g2(NV / 128, 8);
  k_gemm2<<<g2, 256, 0, stream>>>(adjAb, HWt, P2);
  k_bias<<<NV * 128 / 4 / 256, 256, 0, stream>>>(P2, bias, out);
  hipMemcpyAsync(out + (size_t)NV * 128, He, (size_t)NE * 128 * sizeof(float),
                 hipMemcpyDeviceToDevice, stream);
}